// Round 11
// baseline (4321.979 us; speedup 1.0000x reference)
//
#include <hip/hip_runtime.h>

#define TDIM 512
#define BDIM 256
#define IDIM 64
#define HDIM 512
#define PSTR 20   // LDS row stride (16 rows + pad, multiple of 4 for f32x4 writes)

typedef short bf16x8 __attribute__((ext_vector_type(8)));
typedef float f32x4  __attribute__((ext_vector_type(4)));

__device__ __forceinline__ unsigned short f2bf(float f) {
  union { float f; unsigned u; } v; v.f = f;
  return (unsigned short)((v.u + 0x7fffu + ((v.u >> 16) & 1u)) >> 16);
}

__device__ __forceinline__ bf16x8 load8f_bf16(const float* p) {
  float4 a = *(const float4*)p;
  float4 b = *(const float4*)(p + 4);
  bf16x8 r;
  r[0] = (short)f2bf(a.x); r[1] = (short)f2bf(a.y);
  r[2] = (short)f2bf(a.z); r[3] = (short)f2bf(a.w);
  r[4] = (short)f2bf(b.x); r[5] = (short)f2bf(b.y);
  r[6] = (short)f2bf(b.z); r[7] = (short)f2bf(b.w);
  return r;
}

// device-coherent 16B read of 8 bf16 (sc0 sc1: bypass stale L1/L2, served by MALL)
__device__ __forceinline__ bf16x8 load_h16(const unsigned short* p) {
  union { unsigned long long u[2]; bf16x8 v; } r;
  r.u[0] = __hip_atomic_load((const unsigned long long*)p,
                             __ATOMIC_RELAXED, __HIP_MEMORY_SCOPE_AGENT);
  r.u[1] = __hip_atomic_load((const unsigned long long*)(p + 4),
                             __ATOMIC_RELAXED, __HIP_MEMORY_SCOPE_AGENT);
  return r.v;
}

__device__ __forceinline__ float sigm(float x)   { return 1.0f / (1.0f + __expf(-x)); }
__device__ __forceinline__ float tanh_f(float x) { return 2.0f / (1.0f + __expf(-2.0f * x)) - 1.0f; }

// Persistent 2-layer LSTM, merged-round schedule + TWO phase-shifted streams.
// 256 blocks x 256 threads, 1 block/CU. Block (bi=bid&7, hj=bid>>3) handles
// hidden cols [hj*16,+16) for two independent 16-row recurrences:
//   stream 0: batch rows [bi*32, +16)   (flag group 2*bi)
//   stream 1: batch rows [bi*32+16,+16) (flag group 2*bi+1)
// Per loop iteration t: run round t of stream 0 then stream 1. Each stream's
// post->detect MALL latency hides under the other stream's compute.
// Round t of a stream: layer0(t) [x[t], h0[t-1]] + layer1(t-1) [h0[t-1], h1[t-2]].
// h0[2][256][512] parity t&1; h1[2][256][512] parity t&1. Proven R5/R10 MALL
// protocol per stream: wave0-only poll, vmcnt(0) drain -> barrier -> tid0 post.
__global__ __launch_bounds__(256, 1)
void lstm_persist(const float* __restrict__ x,
                  const float* __restrict__ Wih0, const float* __restrict__ Whh0,
                  const float* __restrict__ bih0, const float* __restrict__ bhh0,
                  const float* __restrict__ Wih1, const float* __restrict__ Whh1,
                  const float* __restrict__ bih1, const float* __restrict__ bhh1,
                  unsigned short* __restrict__ h0b, unsigned short* __restrict__ h1b,
                  float* __restrict__ h1f, int* __restrict__ flags)
{
  const int tid  = threadIdx.x;
  const int w    = tid >> 6;          // wave 0..3
  const int lane = tid & 63;
  const int lrow = lane & 15;         // m/n index within fragment
  const int lk8  = (lane >> 4) << 3;  // k offset within 32-chunk
  const int bid  = blockIdx.x;
  const int bi   = bid & 7;           // batch super-group
  const int hj   = bid >> 3;          // col block 0..31

  __shared__ float part[2][2][4 * 64 * PSTR];  // [stream][layer][wave][gatecol][row pad]

  // ---------------- weights -> registers (bf16 fragments), once ----------------
  // wave w owns h-chunks ch = w + 4*s (s=0..3); x-chunk w (w<2).
  bf16x8 bwx[4];        // W_ih0, x chunk (w<2 only)
  bf16x8 bw0h[4][4];    // W_hh0
  bf16x8 bw1a[4][4];    // W_ih1 (input = h0[t-1])
  bf16x8 bw1b[4][4];    // W_hh1 (input = h1[t-2])
  #pragma unroll
  for (int g = 0; g < 4; ++g) {
    int j = g * 512 + hj * 16 + lrow;
    if (w < 2) bwx[g] = load8f_bf16(Wih0 + (size_t)j * 64 + (w * 32 + lk8));
    else       { bf16x8 z = {0,0,0,0,0,0,0,0}; bwx[g] = z; }
    #pragma unroll
    for (int s = 0; s < 4; ++s) {
      int ch = w + 4 * s;
      bw0h[s][g] = load8f_bf16(Whh0 + (size_t)j * 512 + (ch * 32 + lk8));
      bw1a[s][g] = load8f_bf16(Wih1 + (size_t)j * 512 + (ch * 32 + lk8));
      bw1b[s][g] = load8f_bf16(Whh1 + (size_t)j * 512 + (ch * 32 + lk8));
    }
  }

  // ---------------- epilogue mapping ----------------
  // waves 0-1 (tid<128): layer0 epilogue; waves 2-3: layer1 epilogue.
  // Within a half: thread = (row er 0..15, col-pair hp 0..7).
  const int elay = tid >> 7;
  const int hp   = tid & 7;
  const int er   = (tid >> 3) & 15;
  const int jc0  = hj * 16 + 2 * hp;
  const float* bihp = elay ? bih1 : bih0;
  const float* bhhp = elay ? bhh1 : bhh0;
  float bia[2][4];
  #pragma unroll
  for (int cc = 0; cc < 2; ++cc)
    #pragma unroll
    for (int g = 0; g < 4; ++g)
      bia[cc][g] = bihp[g * 512 + jc0 + cc] + bhhp[g * 512 + jc0 + cc];

  float cst[2][2] = {{0.f, 0.f}, {0.f, 0.f}};   // [stream][cc], this thread's layer

  const size_t HB = (size_t)BDIM * HDIM;
  const int r0w = (lane >> 4) << 2;

  #pragma unroll 1
  for (int t = 0; t <= TDIM; ++t) {
    // prefetch x fragments for BOTH streams before any wait
    bf16x8 xf[2];
    #pragma unroll
    for (int ss = 0; ss < 2; ++ss) { bf16x8 z = {0,0,0,0,0,0,0,0}; xf[ss] = z; }
    if (t < TDIM && w < 2) {
      #pragma unroll
      for (int ss = 0; ss < 2; ++ss)
        xf[ss] = load8f_bf16(x + ((size_t)(bi * 32 + ss * 16 + lrow) * TDIM + t) * IDIM + (w * 32 + lk8));
    }

    #pragma unroll
    for (int ss = 0; ss < 2; ++ss) {
      const int gbase = bi * 32 + ss * 16;
      int* words = flags + (bi * 2 + ss) * 32;

      f32x4 acc0[4], acc1[4];
      #pragma unroll
      for (int g = 0; g < 4; ++g) {
        f32x4 z = {0.f,0.f,0.f,0.f}; acc0[g] = z; acc1[g] = z;
      }

      // x GEMM: no recurrent dependency, before the wait
      if (t < TDIM && w < 2) {
        #pragma unroll
        for (int g = 0; g < 4; ++g)
          acc0[g] = __builtin_amdgcn_mfma_f32_16x16x32_bf16(xf[ss], bwx[g], acc0[g], 0, 0, 0);
      }

      // low-pressure wait: wave0 polls this stream's 32 words; others park
      if (w == 0) {
        const int* p = words + (lane & 31);
        while (true) {
          int v = __hip_atomic_load(p, __ATOMIC_RELAXED, __HIP_MEMORY_SCOPE_AGENT);
          if (__all(v >= t)) break;
          __builtin_amdgcn_s_sleep(2);
        }
      }
      __syncthreads();
      asm volatile("" ::: "memory");   // keep h loads below the wait

      // h0[t-1] at parity (t+1)&1 ; h1[t-2] at parity t&1
      const unsigned short* h0p = h0b + (size_t)((t + 1) & 1) * HB;
      const unsigned short* h1p = h1b + (size_t)(t & 1) * HB;

      bf16x8 ah0[4], ah1[4];
      const size_t hrow = (size_t)(gbase + lrow) * HDIM;
      #pragma unroll
      for (int s = 0; s < 4; ++s) {
        int ch = w + 4 * s;
        ah0[s] = load_h16(h0p + hrow + (ch * 32 + lk8));
        ah1[s] = load_h16(h1p + hrow + (ch * 32 + lk8));
      }

      if (t < TDIM) {
        #pragma unroll
        for (int s = 0; s < 4; ++s)
          #pragma unroll
          for (int g = 0; g < 4; ++g)
            acc0[g] = __builtin_amdgcn_mfma_f32_16x16x32_bf16(ah0[s], bw0h[s][g], acc0[g], 0, 0, 0);
      }
      if (t >= 1) {
        #pragma unroll
        for (int s = 0; s < 4; ++s)
          #pragma unroll
          for (int g = 0; g < 4; ++g) {
            acc1[g] = __builtin_amdgcn_mfma_f32_16x16x32_bf16(ah0[s], bw1a[s][g], acc1[g], 0, 0, 0);
            acc1[g] = __builtin_amdgcn_mfma_f32_16x16x32_bf16(ah1[s], bw1b[s][g], acc1[g], 0, 0, 0);
          }
      }

      if (t < TDIM) {
        #pragma unroll
        for (int g = 0; g < 4; ++g)
          *(f32x4*)&part[ss][0][(w * 64 + g * 16 + lrow) * PSTR + r0w] = acc0[g];
      }
      if (t >= 1) {
        #pragma unroll
        for (int g = 0; g < 4; ++g)
          *(f32x4*)&part[ss][1][(w * 64 + g * 16 + lrow) * PSTR + r0w] = acc1[g];
      }
      __syncthreads();

      // -------- epilogue, layer-split across wave halves --------
      const bool act = elay ? (t >= 1) : (t < TDIM);
      if (act) {
        const float* pp = &part[ss][elay][0];
        float hv[2];
        #pragma unroll
        for (int cc = 0; cc < 2; ++cc) {
          int hc = 2 * hp + cc;
          float gv[4];
          #pragma unroll
          for (int g = 0; g < 4; ++g) {
            float sum = bia[cc][g];
            #pragma unroll
            for (int w4 = 0; w4 < 4; ++w4)
              sum += pp[(w4 * 64 + g * 16 + hc) * PSTR + er];
            gv[g] = sum;
          }
          float ig = sigm(gv[0]), fg = sigm(gv[1]), gg = tanh_f(gv[2]), og = sigm(gv[3]);
          cst[ss][cc] = fg * cst[ss][cc] + ig * gg;
          hv[cc] = og * tanh_f(cst[ss][cc]);
        }
        unsigned packed = (unsigned)f2bf(hv[0]) | ((unsigned)f2bf(hv[1]) << 16);
        // layer0 writes h0[t] (parity t&1); layer1 writes h1[t-1] (parity (t+1)&1)
        unsigned short* hw = elay ? (h1b + (size_t)((t + 1) & 1) * HB)
                                  : (h0b + (size_t)(t & 1) * HB);
        __hip_atomic_store((unsigned*)(hw + (size_t)(gbase + er) * HDIM + jc0), packed,
                           __ATOMIC_RELAXED, __HIP_MEMORY_SCOPE_AGENT);
        if (elay && t == TDIM) {
          float2 o; o.x = hv[0]; o.y = hv[1];
          *(float2*)(h1f + (size_t)(gbase + er) * HDIM + jc0) = o;
        }
      }

      asm volatile("s_waitcnt vmcnt(0)" ::: "memory");  // h stores device-visible
      __syncthreads();                                  // all waves drained
      if (tid == 0)
        __hip_atomic_store(&words[hj], t + 1, __ATOMIC_RELAXED, __HIP_MEMORY_SCOPE_AGENT);
    }
  }
}

// out[b] = h1f[b,:] . Wlin + blin ; out[256] = mean((out - y)^2)
__global__ void head_k(const float* __restrict__ h1f, const float* __restrict__ Wlin,
                       const float* __restrict__ blin, const float* __restrict__ y,
                       float* __restrict__ dout)
{
  __shared__ float red[256];
  int b = threadIdx.x;
  const float4* hp = (const float4*)(h1f + (size_t)b * HDIM);
  const float4* wp = (const float4*)Wlin;
  float acc = 0.f;
  #pragma unroll 8
  for (int i = 0; i < HDIM / 4; ++i) {
    float4 h4 = hp[i]; float4 w4 = wp[i];
    acc += h4.x * w4.x + h4.y * w4.y + h4.z * w4.z + h4.w * w4.w;
  }
  float o = acc + blin[0];
  dout[b] = o;
  float d = o - y[b];
  red[b] = d * d;
  __syncthreads();
  for (int off = 128; off > 0; off >>= 1) {
    if (b < off) red[b] += red[b + off];
    __syncthreads();
  }
  if (b == 0) dout[256] = red[0] * (1.0f / 256.0f);
}

extern "C" void kernel_launch(void* const* d_in, const int* in_sizes, int n_in,
                              void* d_out, int out_size, void* d_ws, size_t ws_size,
                              hipStream_t stream)
{
  const float* x    = (const float*)d_in[0];
  const float* y    = (const float*)d_in[1];
  const float* Wih0 = (const float*)d_in[2];
  const float* Whh0 = (const float*)d_in[3];
  const float* bih0 = (const float*)d_in[4];
  const float* bhh0 = (const float*)d_in[5];
  const float* Wih1 = (const float*)d_in[6];
  const float* Whh1 = (const float*)d_in[7];
  const float* bih1 = (const float*)d_in[8];
  const float* bhh1 = (const float*)d_in[9];
  const float* Wlin = (const float*)d_in[10];
  const float* blin = (const float*)d_in[11];

  char* ws = (char*)d_ws;
  unsigned short* h0b = (unsigned short*)ws;             // 2*256*512*2 = 524,288 B
  unsigned short* h1b = (unsigned short*)(ws + 524288);  // 524,288 B
  int*   flags = (int*)(ws + 1048576);                   // 16 groups * 32 words = 2 KB (4 KB pad)
  float* h1f   = (float*)(ws + 1048576 + 4096);          // 256*512*4 = 524,288 B

  // zero h buffers (h[-1]=h[-2]=0) + flag words every call (graph-replay safe)
  hipMemsetAsync(d_ws, 0, 1048576 + 4096, stream);

  hipLaunchKernelGGL(lstm_persist, dim3(256), dim3(256), 0, stream,
                     x, Wih0, Whh0, bih0, bhh0, Wih1, Whh1, bih1, bhh1,
                     h0b, h1b, h1f, flags);
  hipLaunchKernelGGL(head_k, dim3(1), dim3(256), 0, stream,
                     h1f, Wlin, blin, y, (float*)d_out);
}